// Round 1
// baseline (232.450 us; speedup 1.0000x reference)
//
#include <hip/hip_runtime.h>

#define NUM_EMB 2048
#define DIM     128
#define NVEC    65536            // 64*32*32
// MARGIN: needs >= 2*approx_err + fp32-bucket slop (~2.6e-4). 1e-3 = 4x
// headroom. Proven R7/R8: absmax 0.0. DO NOT ENLARGE (R6's 4e-3 -> 1.9 ms rerank).
// R10: capture reformulated in v-space (v = dot - enorm/2); threshold uses
// MARGIN/2 in v-units == MARGIN in distance units. Identical capture set.
#define MARGIN  1.0e-3f
#define CAP     32               // candidates/row; overflow -> cooperative block scan (~dead at 1e-3)
#define CHUNK   256              // codes per LDS chunk in approx
#define NCHUNK  (NUM_EMB / CHUNK)
#define ES      136              // ushort stride/code in LDS: 272 B, 16B-aligned, 2-way banks (free)
#define ZS      132              // float stride/z-row in LDS

typedef float  f32x4 __attribute__((ext_vector_type(4)));
typedef short  s16x8 __attribute__((ext_vector_type(8)));

// RNE float -> bf16 (finite inputs)
__device__ __forceinline__ ushort f2bf(float f) {
    unsigned u = __float_as_uint(f);
    u = (u + 0x7fffu + ((u >> 16) & 1u)) >> 16;
    return (ushort)u;
}

// ---------------------------------------------------------------------------
// numpy pairwise_sum replica for n=128 fp32 applied to v*v (bit-exact vs np —
// verified R2-R8 absmax 0.0).  DO NOT REASSOCIATE.
// ---------------------------------------------------------------------------
__device__ __forceinline__ float np_pairwise_sumsq_128(const float* __restrict__ p)
{
    float r[8];
    #pragma unroll
    for (int j = 0; j < 8; ++j) { float v = p[j]; r[j] = __fmul_rn(v, v); }
    #pragma unroll
    for (int i = 8; i < 128; i += 8)
        #pragma unroll
        for (int j = 0; j < 8; ++j) { float v = p[i + j]; r[j] = __fadd_rn(r[j], __fmul_rn(v, v)); }
    float s01 = __fadd_rn(r[0], r[1]);
    float s23 = __fadd_rn(r[2], r[3]);
    float s45 = __fadd_rn(r[4], r[5]);
    float s67 = __fadd_rn(r[6], r[7]);
    return __fadd_rn(__fadd_rn(s01, s23), __fadd_rn(s45, s67));
}

// exact fp32-replica dot over one 32-k slab (ascending k, single accumulator)
__device__ __forceinline__ float dot_seg(const float4* __restrict__ zp,
                                         const float4* __restrict__ ep,
                                         int seg, float dot)
{
    float4 e[8], zz[8];
    #pragma unroll
    for (int i = 0; i < 8; ++i) { e[i] = ep[seg * 8 + i]; zz[i] = zp[seg * 8 + i]; }
    #pragma unroll
    for (int i = 0; i < 8; ++i) {
        dot = fmaf(zz[i].x, e[i].x, dot);
        dot = fmaf(zz[i].y, e[i].y, dot);
        dot = fmaf(zz[i].z, e[i].z, dot);
        dot = fmaf(zz[i].w, e[i].w, dot);
    }
    return dot;
}

// ---------------------------------------------------------------------------
// Kernel 1: enorm (np-exact) + emb->bf16 + zero accum/cand_cnt
// ---------------------------------------------------------------------------
__global__ __launch_bounds__(256)
void prep_kernel(const float* __restrict__ emb,
                 float* __restrict__ enorm,
                 float* __restrict__ accum,
                 unsigned* __restrict__ cand_cnt,
                 ushort* __restrict__ emb_bf)
{
    int g = blockIdx.x * 256 + threadIdx.x;
    cand_cnt[g] = 0u;
    if (g == 0) *accum = 0.0f;

    float4 v = ((const float4*)emb)[g];          // 65536 float4 == full emb
    ushort4 b;
    b.x = f2bf(v.x); b.y = f2bf(v.y); b.z = f2bf(v.z); b.w = f2bf(v.w);
    ((ushort4*)emb_bf)[g] = b;

    if (g < NUM_EMB)
        enorm[g] = np_pairwise_sumsq_128(emb + (size_t)g * DIM);
}

// ---------------------------------------------------------------------------
// Kernel 2: bf16-MFMA approx filter, single capture pass with running
// row-threshold (seed visit on chunk 0).
//
// R10 restructure (LDS-read-amplification fix):
//   R9 had 16 waves x 16 rows, every wave reading the FULL chunk from LDS ->
//   1024 ds_read_b128/CU/visit (~12.3k cy of the 27.8k cy visit wall, + 4096
//   cy bank-conflict overhead; rocprof: MfmaUtil 14%, VALUBusy 19%, all pipes
//   idle-ish => LDS-read-path + latency bound).
//   Now: 16 waves = 8 row-groups x 2 code-halves. Each wave owns 32 rows
//   (two 16-row M-tiles sharing every B-fragment) x 128 codes/chunk ->
//   32 reads/wave/visit, 512/CU/visit (HALVED) at the SAME 16 waves/CU
//   occupancy (the R7->R8 lesson: throughput scales with resident waves).
//   Wave pairs (w, w^1) merge per-row running maxima through vS[] each visit,
//   so the capture threshold stays globally tight through visit v-1 ==
//   identical capture semantics to R9.
//   Also: -0.5*enorm folded into the MFMA accumulator init => epilogue is
//   fmax+cmp only (no per-element fmaf); capture in v-space, thr = vmax-M/2.
// MFMA 16x16x32 bf16 layouts HW-verified (m89/m91).
// ---------------------------------------------------------------------------
__global__ __launch_bounds__(1024, 1)
void approx_kernel(const float* __restrict__ z,
                   const ushort* __restrict__ emb_bf,
                   const float* __restrict__ enorm,
                   unsigned* __restrict__ cand_cnt,
                   ushort* __restrict__ cand)
{
    __shared__ __align__(16) ushort eS[CHUNK * ES];   // 69,632 B
    __shared__ float cS[CHUNK];                       // -0.5*enorm of chunk
    __shared__ float vS[16][32];                      // per-wave row maxima (pair exchange)

    const int tid  = threadIdx.x;         // 0..1023
    const int w    = tid >> 6;            // wave 0..15
    const int lane = tid & 63;
    const int col  = lane & 15;           // m (A frag) / n (B frag) / D col
    const int quad = lane >> 4;           // k-group / D row-group
    const int rg   = w >> 1;              // row-group 0..7 (32 rows each)
    const int ch   = w & 1;               // code-half 0..1 (128 codes each)
    const int rowbase = blockIdx.x * 256 + rg * 32;

    // A-fragments: 2 row-tiles x 4 k-tiles, loaded once, fp32->bf16
    s16x8 afrag[2][4];
    #pragma unroll
    for (int rt = 0; rt < 2; ++rt) {
        const float* zr = z + (size_t)(rowbase + rt * 16 + col) * DIM;
        #pragma unroll
        for (int kt = 0; kt < 4; ++kt) {
            const float4* p = (const float4*)(zr + kt * 32 + quad * 8);
            float4 f0 = p[0], f1 = p[1];
            s16x8 a;
            a[0] = (short)f2bf(f0.x); a[1] = (short)f2bf(f0.y);
            a[2] = (short)f2bf(f0.z); a[3] = (short)f2bf(f0.w);
            a[4] = (short)f2bf(f1.x); a[5] = (short)f2bf(f1.y);
            a[6] = (short)f2bf(f1.z); a[7] = (short)f2bf(f1.w);
            afrag[rt][kt] = a;
        }
    }

    const ushort* eH = eS + ch * 128 * ES;   // this wave's code-half in LDS
    const float*  cH = cS + ch * 128;

    // vmax[i], i = rt*4+r  ->  local row = rt*16 + quad*4 + r  (v = dot - C/2)
    float vmax[8], thr[8];
    #pragma unroll
    for (int i = 0; i < 8; ++i) { vmax[i] = -3.0e38f; thr[i] = 3.0e38f; }

    // 9 chunk-visits: visit 0 = seed (chunk 0, max only), visits 1..8 = capture
    for (int vis = 0; vis < 9; ++vis) {
        const int c = (vis == 0) ? 0 : (vis - 1);
        __syncthreads();                 // previous chunk's readers done; vS visible

        // fold partner half's row maxima (through visit vis-1) -> tight thr
        if (vis > 0) {
            #pragma unroll
            for (int i = 0; i < 8; ++i) {
                float v = fmaxf(vmax[i], vS[w ^ 1][(i >> 2) * 16 + quad * 4 + (i & 3)]);
                vmax[i] = v;
                thr[i]  = v - 0.5f * MARGIN;
            }
        }

        const uint4* src = (const uint4*)(emb_bf + (size_t)c * CHUNK * DIM);
        #pragma unroll
        for (int i = 0; i < 4; ++i) {
            int li   = i * 1024 + tid;            // 0..4095
            int code = li >> 4, fc = li & 15;
            *(uint4*)&eS[code * ES + fc * 8] = src[li];
        }
        if (tid < CHUNK) cS[tid] = -0.5f * enorm[c * CHUNK + tid];
        __syncthreads();

        #pragma unroll 4
        for (int t = 0; t < 8; ++t) {            // 8 x 16 codes = this wave's half
            s16x8 bfrag[4];
            #pragma unroll
            for (int kt = 0; kt < 4; ++kt)
                bfrag[kt] = *(const s16x8*)&eH[(t * 16 + col) * ES + kt * 32 + quad * 8];

            float h = cH[t * 16 + col];          // -0.5*enorm of this code
            f32x4 a0 = {h, h, h, h};
            f32x4 a1 = {h, h, h, h};
            #pragma unroll
            for (int kt = 0; kt < 4; ++kt) {
                a0 = __builtin_amdgcn_mfma_f32_16x16x32_bf16(afrag[0][kt], bfrag[kt], a0, 0, 0, 0);
                a1 = __builtin_amdgcn_mfma_f32_16x16x32_bf16(afrag[1][kt], bfrag[kt], a1, 0, 0, 0);
            }

            const int code_g = c * CHUNK + ch * 128 + t * 16 + col;
            #pragma unroll
            for (int r = 0; r < 4; ++r) {
                float v0 = a0[r];
                vmax[r] = fmaxf(vmax[r], v0);
                if (vis > 0 && v0 >= thr[r]) {
                    int row_g = rowbase + quad * 4 + r;
                    unsigned pos = atomicAdd(&cand_cnt[row_g], 1u);
                    if (pos < CAP) cand[(size_t)row_g * CAP + pos] = (ushort)code_g;
                }
                float v1 = a1[r];
                vmax[4 + r] = fmaxf(vmax[4 + r], v1);
                if (vis > 0 && v1 >= thr[4 + r]) {
                    int row_g = rowbase + 16 + quad * 4 + r;
                    unsigned pos = atomicAdd(&cand_cnt[row_g], 1u);
                    if (pos < CAP) cand[(size_t)row_g * CAP + pos] = (ushort)code_g;
                }
            }
        }

        // refresh row-wide max across the 16 cols, then publish for partner
        #pragma unroll
        for (int i = 0; i < 8; ++i) {
            float v = vmax[i];
            v = fmaxf(v, __shfl_xor(v, 1, 64));
            v = fmaxf(v, __shfl_xor(v, 2, 64));
            v = fmaxf(v, __shfl_xor(v, 4, 64));
            v = fmaxf(v, __shfl_xor(v, 8, 64));
            vmax[i] = v;
            thr[i]  = v - 0.5f * MARGIN;
        }
        if (col == 0) {
            #pragma unroll
            for (int i = 0; i < 8; ++i)
                vS[w][(i >> 2) * 16 + quad * 4 + (i & 3)] = vmax[i];
        }
    }
}

// ---------------------------------------------------------------------------
// Kernel 3: exact fp32-replica re-rank + cooperative overflow scan + fused
// gather/loss epilogue (unchanged from R6/R7/R8 — verified).
// ---------------------------------------------------------------------------
__global__ __launch_bounds__(256)
void rerank_kernel(const float* __restrict__ z,
                   const float* __restrict__ emb,
                   const float* __restrict__ enorm,
                   const unsigned* __restrict__ cand_cnt,
                   const ushort* __restrict__ cand,
                   float* __restrict__ out_q,
                   float* __restrict__ out_idx_f,
                   float* __restrict__ accum)
{
    __shared__ float zs[64 * ZS];        // 33,792 B
    __shared__ float As[64];
    __shared__ int   bidx[64];
    __shared__ int   ovf_list[64];
    __shared__ int   ovf_n;
    __shared__ float rv[4];
    __shared__ int   rvi[4];
    __shared__ float wsum[4];

    const int tid = threadIdx.x;
    const int m0  = blockIdx.x * 64;
    if (tid == 0) ovf_n = 0;

    // stage z tile, coalesced
    #pragma unroll
    for (int i = 0; i < 8; ++i) {
        int li = tid + i * 256;          // 0..2047
        int m  = li >> 5, dc = li & 31;
        float4 v = ((const float4*)(z + (size_t)(m0 + m) * DIM))[dc];
        *(float4*)&zs[m * ZS + dc * 4] = v;
    }
    __syncthreads();
    if (tid < 64) As[tid] = np_pairwise_sumsq_128(&zs[tid * ZS]);
    __syncthreads();

    const int row_l = tid >> 2;          // 4 contiguous lanes per row
    const int sub   = tid & 3;
    const int row_g = m0 + row_l;
    const unsigned cnt = cand_cnt[row_g];
    const float A = As[row_l];
    const float4* zp = (const float4*)&zs[row_l * ZS];

    float bv = 3.0e38f;
    int   bi = 0x7fffffff;

    if (cnt <= CAP) {                    // candidate path (split over 4 lanes)
        for (unsigned ci = sub; ci < cnt; ci += 4) {
            int j = (int)cand[(size_t)row_g * CAP + ci];
            const float4* ep = (const float4*)(emb + (size_t)j * DIM);
            float dot = 0.0f;
            #pragma unroll
            for (int seg = 0; seg < 4; ++seg) dot = dot_seg(zp, ep, seg, dot);
            float t1 = fmaf(-2.0f, dot, A);
            float s  = __fadd_rn(t1, enorm[j]);
            if (s < bv || (s == bv && j < bi)) { bv = s; bi = j; }
        }
    }
    // (val,idx) min-reduce across the 4 lanes of this row
    #pragma unroll
    for (int off = 1; off <= 2; off <<= 1) {
        float v  = __shfl_xor(bv, off, 64);
        int   ix = __shfl_xor(bi, off, 64);
        if (v < bv || (v == bv && ix < bi)) { bv = v; bi = ix; }
    }
    if (sub == 0) {
        if (cnt <= CAP) bidx[row_l] = bi;
        else { int p = atomicAdd(&ovf_n, 1); ovf_list[p] = row_l; }
    }
    __syncthreads();

    // cooperative exact scan of overflow rows: 256 thr x 8 ascending codes
    const int n_ovf = ovf_n;
    for (int o = 0; o < n_ovf; ++o) {
        const int rl = ovf_list[o];
        const float Ar = As[rl];
        const float4* zp2 = (const float4*)&zs[rl * ZS];
        float bv2 = 3.0e38f;
        int   bi2 = 0x7fffffff;
        for (int jj = 0; jj < 8; ++jj) {
            int j = tid * 8 + jj;        // ascending within thread -> strict <
            const float4* ep = (const float4*)(emb + (size_t)j * DIM);
            float dot = 0.0f;
            #pragma unroll
            for (int seg = 0; seg < 4; ++seg) dot = dot_seg(zp2, ep, seg, dot);
            float t1 = fmaf(-2.0f, dot, Ar);
            float s  = __fadd_rn(t1, enorm[j]);
            if (s < bv2) { bv2 = s; bi2 = j; }
        }
        #pragma unroll
        for (int off = 1; off < 64; off <<= 1) {
            float v  = __shfl_xor(bv2, off, 64);
            int   ix = __shfl_xor(bi2, off, 64);
            if (v < bv2 || (v == bv2 && ix < bi2)) { bv2 = v; bi2 = ix; }
        }
        if ((tid & 63) == 0) { rv[tid >> 6] = bv2; rvi[tid >> 6] = bi2; }
        __syncthreads();
        if (tid == 0) {
            float fv = rv[0]; int fi = rvi[0];
            #pragma unroll
            for (int ww = 1; ww < 4; ++ww) {
                if (rv[ww] < fv || (rv[ww] == fv && rvi[ww] < fi)) { fv = rv[ww]; fi = rvi[ww]; }
            }
            bidx[rl] = fi;
        }
        __syncthreads();
    }

    if (tid < 64) out_idx_f[m0 + tid] = (float)bidx[tid];

    // fused gather + straight-through + loss partial (zs still intact)
    float part = 0.0f;
    #pragma unroll
    for (int i = 0; i < 8; ++i) {
        int li = tid + i * 256;
        int m  = li >> 5, dc = li & 31;
        int j  = bidx[m];
        float4 q  = ((const float4*)(emb + (size_t)j * DIM))[dc];
        float4 zv = *(const float4*)&zs[m * ZS + dc * 4];
        float4 o;
        o.x = __fadd_rn(zv.x, __fsub_rn(q.x, zv.x));
        o.y = __fadd_rn(zv.y, __fsub_rn(q.y, zv.y));
        o.z = __fadd_rn(zv.z, __fsub_rn(q.z, zv.z));
        o.w = __fadd_rn(zv.w, __fsub_rn(q.w, zv.w));
        ((float4*)out_q)[(size_t)(m0 + m) * 32 + dc] = o;
        float dx = q.x - zv.x, dy = q.y - zv.y, dz = q.z - zv.z, dw = q.w - zv.w;
        part += dx * dx + dy * dy + dz * dz + dw * dw;
    }
    #pragma unroll
    for (int off = 32; off > 0; off >>= 1)
        part += __shfl_down(part, off, 64);
    if ((tid & 63) == 0) wsum[tid >> 6] = part;
    __syncthreads();
    if (tid == 0) atomicAdd(accum, wsum[0] + wsum[1] + wsum[2] + wsum[3]);
}

// ---------------------------------------------------------------------------
// Kernel 4: loss = (1 + beta) * sum / (N*D), beta = 0.25
// ---------------------------------------------------------------------------
__global__ void finalize_kernel(const float* __restrict__ accum,
                                float* __restrict__ out_loss)
{
    *out_loss = 1.25f * (*accum) / 8388608.0f;
}

// ---------------------------------------------------------------------------
extern "C" void kernel_launch(void* const* d_in, const int* in_sizes, int n_in,
                              void* d_out, int out_size, void* d_ws, size_t ws_size,
                              hipStream_t stream)
{
    const float* z   = (const float*)d_in[0];   // [65536,128]
    const float* emb = (const float*)d_in[1];   // [2048,128]
    float* out = (float*)d_out;                 // q(8388608) | idx-as-f32(65536) | loss(1)

    char*     ws       = (char*)d_ws;
    float*    enorm    = (float*)ws;                          // 8 KB
    float*    accum    = (float*)(ws + 8192);
    unsigned* cand_cnt = (unsigned*)(ws + 16384);             // 256 KB
    ushort*   cand     = (ushort*)(ws + 16384 + 262144);      // 4 MB
    ushort*   emb_bf   = (ushort*)(ws + 16384 + 262144 + 4194304);  // 512 KB

    prep_kernel   <<<NVEC / 256, 256,  0, stream>>>(emb, enorm, accum, cand_cnt, emb_bf);
    approx_kernel <<<256,        1024, 0, stream>>>(z, emb_bf, enorm, cand_cnt, cand);
    rerank_kernel <<<NVEC / 64,  256,  0, stream>>>(z, emb, enorm, cand_cnt, cand,
                                                    out, out + 8388608, accum);
    finalize_kernel<<<1, 1, 0, stream>>>(accum, out + 8388608 + 65536);
}